// Round 10
// baseline (252.996 us; speedup 1.0000x reference)
//
#include <hip/hip_runtime.h>
#include <hip/hip_fp16.h>

// ---------------------------------------------------------------------------
// IN=128, H=8, R=16, D=16 -> H*R = H*D = 128
// K = h @ q, Q = h @ p, V = h @ Wv   (K uses weight "q", Q uses weight "p")
// score = exp(clip((K[src]*Q[dst]).sum(r)/4, -5, 5))
// out = seg_sum(score*V[src], dst) / max(seg_sum(score,dst), eps-fixup)
//
// GEMM: mfma_f32_16x16x32_f16, A=W / B=h so each lane's C frag = 4 consecutive
// output cols of one node -> in-register fp16 pack, direct stores.
// KV interleaved fp16 (512B/row): quad q -> uints {4q,4q+1}=K, {4q+2,4q+3}=V.
// Aggregate: wave per node, 2 edge slots (lane=32*eh+l) + DOUBLE-BUFFERED
// prefetch (2 outstanding dwordx4/lane) - the gather is MLP-limited.
// CSR: bucket scatter with rank-in-register (single LDS-atomic pass), packed
// 4B entries (dlocal<<18|src, needs N<2^18); fine sort also rank-reuse.
// ---------------------------------------------------------------------------

#define HNODE 64        // nodes per GEMM block
#define EPB   8192      // edges per block in bucket scatter
#define BKT_SHIFT 7     // 128 nodes per bucket
#define BKT_CAP 5120    // >= bucket mean 4092 + 16 sigma; 5120/256 = 20 slots

typedef _Float16 f16x8 __attribute__((ext_vector_type(8)));
typedef float    f32x4 __attribute__((ext_vector_type(4)));
typedef _Float16 hv2   __attribute__((ext_vector_type(2)));

__device__ __forceinline__ float fdot2(unsigned a, unsigned b, float c) {
#if __has_builtin(__builtin_amdgcn_fdot2)
    return __builtin_amdgcn_fdot2(__builtin_bit_cast(hv2, a),
                                  __builtin_bit_cast(hv2, b), c, false);
#else
    __half2 ah = *(__half2*)&a, bh = *(__half2*)&b;
    float2 af = __half22float2(ah), bf = __half22float2(bh);
    return c + af.x * bf.x + af.y * bf.y;
#endif
}

__device__ __forceinline__ float2 h2f(unsigned u) {
    __half2 hh = *(__half2*)&u;
    return __half22float2(hh);
}

__device__ __forceinline__ unsigned pack2(float a, float b) {
    __half2 hh = __floats2half2_rn(a, b);
    return *(unsigned*)&hh;
}

// ---------------- Weight transpose+convert: W[k][n] fp32 -> Wt[m][n][k] fp16
__global__ __launch_bounds__(256) void wt_convert_kernel(
    const float* __restrict__ Wq, const float* __restrict__ Wp,
    const float* __restrict__ Wv, __half* __restrict__ Wt)
{
    int o = blockIdx.x * 256 + threadIdx.x;      // 3*128*128 total
    int m = o >> 14, rem = o & 16383;
    int nn = rem >> 7, kk = rem & 127;
    const float* W = (m == 0) ? Wq : (m == 1) ? Wp : Wv;
    Wt[o] = __float2half(W[kk * 128 + nn]);
}

// ---------------- MFMA GEMM: h @ {q,p,Wv} -> KV interleaved + Q -------------
__global__ __launch_bounds__(256) void gemm_kqv_kernel(
    const float* __restrict__ h, const __half* __restrict__ Wt,
    unsigned* __restrict__ KV, __half* __restrict__ Q, int n)
{
    __shared__ __align__(16) _Float16 ws[128 * 136];   // one weight matrix

    const int t = threadIdx.x;
    const int wid = t >> 6, lane = t & 63;
    const int node0 = blockIdx.x * HNODE;
    const int mrow = lane & 15, quad = lane >> 4;

    const int row = node0 + wid * 16 + mrow;
    const bool rowvalid = (row < n);
    const int rowc = rowvalid ? row : (n - 1);

    f16x8 hfr[4];
    #pragma unroll
    for (int s = 0; s < 4; s++) {
        const float4* hp = (const float4*)(h + (size_t)rowc * 128 + quad * 8 + 32 * s);
        float4 f0 = hp[0], f1 = hp[1];
        f16x8 a;
        a[0] = (_Float16)f0.x; a[1] = (_Float16)f0.y;
        a[2] = (_Float16)f0.z; a[3] = (_Float16)f0.w;
        a[4] = (_Float16)f1.x; a[5] = (_Float16)f1.y;
        a[6] = (_Float16)f1.z; a[7] = (_Float16)f1.w;
        hfr[s] = a;
    }

    f32x4 acc[3][8];
    #pragma unroll
    for (int m = 0; m < 3; m++)
        #pragma unroll
        for (int ct = 0; ct < 8; ct++) acc[m][ct] = (f32x4){0.f, 0.f, 0.f, 0.f};

    #pragma unroll
    for (int m = 0; m < 3; m++) {
        __syncthreads();
        {
            const uint4* wg = (const uint4*)(Wt + (size_t)m * 16384);
            #pragma unroll
            for (int i = 0; i < 8; i++) {
                int idx = t * 8 + i;            // 0..2047
                int r = idx >> 4, seg = idx & 15;
                *(uint4*)(ws + r * 136 + seg * 8) = wg[idx];
            }
        }
        __syncthreads();
        #pragma unroll
        for (int s = 0; s < 4; s++) {
            #pragma unroll
            for (int ct = 0; ct < 8; ct++) {
                f16x8 a = *(const f16x8*)(ws + (ct * 16 + mrow) * 136 + quad * 8 + 32 * s);
                acc[m][ct] = __builtin_amdgcn_mfma_f32_16x16x32_f16(a, hfr[s], acc[m][ct], 0, 0, 0);
            }
        }
    }

    if (rowvalid) {
        unsigned* kvrow = KV + (size_t)row * 128;
        __half*   qrow  = Q  + (size_t)row * 128;
        #pragma unroll
        for (int ct = 0; ct < 8; ct++) {
            int qd = ct * 4 + quad;            // quad index 0..31
            uint4 ov;
            ov.x = pack2(acc[0][ct][0], acc[0][ct][1]);   // K pair
            ov.y = pack2(acc[0][ct][2], acc[0][ct][3]);
            ov.z = pack2(acc[2][ct][0], acc[2][ct][1]);   // V pair
            ov.w = pack2(acc[2][ct][2], acc[2][ct][3]);
            *(uint4*)(kvrow + 4 * qd) = ov;
            uint2 qv;
            qv.x = pack2(acc[1][ct][0], acc[1][ct][1]);
            qv.y = pack2(acc[1][ct][2], acc[1][ct][3]);
            *(uint2*)(qrow + 4 * qd) = qv;
        }
    }
}

// ---------------- CSR: bucket scatter, single LDS-atomic pass ---------------
// Per-edge rank captured from the histogram atomic (registers); entry packed
// to 4B: (dst&127)<<18 | src   (requires src < 2^18).
__global__ __launch_bounds__(256) void bucket_scatter_kernel(
    const int* __restrict__ src, const int* __restrict__ dst,
    int* __restrict__ bucket_cursor, unsigned* __restrict__ ebuf, int E, int nbkt)
{
    __shared__ int cnt[512];
    __shared__ int start[512];
    int t = threadIdx.x;
    for (int i = t; i < nbkt; i += 256) cnt[i] = 0;
    __syncthreads();

    int4 sv[8], dv[8], rk[8];
    int base = blockIdx.x * EPB + t * 4;
    #pragma unroll
    for (int r = 0; r < 8; r++) {
        int i = base + r * 1024;
        if (i + 3 < E) {
            sv[r] = *(const int4*)(src + i);
            dv[r] = *(const int4*)(dst + i);
        } else {
            int ts[4], td[4];
            for (int k = 0; k < 4; k++) {
                int j = i + k;
                ts[k] = (j < E) ? src[j] : 0;
                td[k] = (j < E) ? dst[j] : -1;
            }
            sv[r] = make_int4(ts[0], ts[1], ts[2], ts[3]);
            dv[r] = make_int4(td[0], td[1], td[2], td[3]);
        }
        rk[r].x = (dv[r].x >= 0) ? atomicAdd(&cnt[dv[r].x >> BKT_SHIFT], 1) : 0;
        rk[r].y = (dv[r].y >= 0) ? atomicAdd(&cnt[dv[r].y >> BKT_SHIFT], 1) : 0;
        rk[r].z = (dv[r].z >= 0) ? atomicAdd(&cnt[dv[r].z >> BKT_SHIFT], 1) : 0;
        rk[r].w = (dv[r].w >= 0) ? atomicAdd(&cnt[dv[r].w >> BKT_SHIFT], 1) : 0;
    }
    __syncthreads();
    for (int i = t; i < nbkt; i += 256) {
        int c = cnt[i];
        start[i] = c ? atomicAdd(&bucket_cursor[i], c) : 0;
    }
    __syncthreads();
    #pragma unroll
    for (int r = 0; r < 8; r++) {
        int s, d, b, pos;
        d = dv[r].x; if (d >= 0) { s = sv[r].x; b = d >> BKT_SHIFT; pos = start[b] + rk[r].x; if (pos < BKT_CAP) ebuf[(size_t)b * BKT_CAP + pos] = ((unsigned)(d & 127) << 18) | (unsigned)s; }
        d = dv[r].y; if (d >= 0) { s = sv[r].y; b = d >> BKT_SHIFT; pos = start[b] + rk[r].y; if (pos < BKT_CAP) ebuf[(size_t)b * BKT_CAP + pos] = ((unsigned)(d & 127) << 18) | (unsigned)s; }
        d = dv[r].z; if (d >= 0) { s = sv[r].z; b = d >> BKT_SHIFT; pos = start[b] + rk[r].z; if (pos < BKT_CAP) ebuf[(size_t)b * BKT_CAP + pos] = ((unsigned)(d & 127) << 18) | (unsigned)s; }
        d = dv[r].w; if (d >= 0) { s = sv[r].w; b = d >> BKT_SHIFT; pos = start[b] + rk[r].w; if (pos < BKT_CAP) ebuf[(size_t)b * BKT_CAP + pos] = ((unsigned)(d & 127) << 18) | (unsigned)s; }
    }
}

// ---------------- Fine sort within bucket (rank-reuse, no 2nd atomic pass) --
__global__ __launch_bounds__(256) void fine_scatter_kernel(
    const unsigned* __restrict__ ebuf, const int* __restrict__ bucket_cursor,
    int2* __restrict__ offs, int* __restrict__ csr, int N, int nbkt)
{
    __shared__ int ldeg[128];
    __shared__ int lstart[128];
    int b = blockIdx.x, t = threadIdx.x;
    int node_base = b << BKT_SHIFT;
    int seg0 = b * BKT_CAP;
    int cnt = bucket_cursor[b];
    if (cnt > BKT_CAP) cnt = BKT_CAP;

    if (t < 128) ldeg[t] = 0;
    __syncthreads();

    unsigned pv[20];
    int rk[20];
    #pragma unroll
    for (int j = 0; j < 20; j++) {
        int i = t + j * 256;
        bool ok = (i < cnt);
        unsigned v = ok ? ebuf[seg0 + i] : 0u;
        pv[j] = v;
        rk[j] = ok ? atomicAdd(&ldeg[v >> 18], 1) : 0;
    }
    __syncthreads();

    int mydeg = (t < 128) ? ldeg[t] : 0;
    for (int off = 1; off < 128; off <<= 1) {
        int y = (t >= off && t < 128) ? ldeg[t - off] : 0;
        __syncthreads();
        if (t < 128) ldeg[t] += y;
        __syncthreads();
    }
    if (t < 128) {
        int gbeg = seg0 + ldeg[t] - mydeg;
        lstart[t] = gbeg;
        int node = node_base + t;
        if (node < N) offs[node] = make_int2(gbeg, gbeg + mydeg);
    }
    __syncthreads();

    #pragma unroll
    for (int j = 0; j < 20; j++) {
        int i = t + j * 256;
        if (i < cnt)
            csr[lstart[pv[j] >> 18] + rk[j]] = (int)(pv[j] & 0x3FFFFu);
    }
}

// ---------------- Aggregation: wave/node, 2 slots, double-buffered prefetch -
// lane = 32*eh + l. Two uint4 buffers per lane => 2 outstanding gathers
// (prefetch distance 4 edges). Dot reduce: xor 1,2; final xor-32 slot merge.
__global__ __launch_bounds__(256) void aggregate_kernel(
    const uint4* __restrict__ KV, const uint2* __restrict__ Qr,
    const int2* __restrict__ offs, const int* __restrict__ csr,
    float4* __restrict__ out, int n)
{
    int t = threadIdx.x;
    int node = blockIdx.x * 4 + (t >> 6);
    if (node >= n) return;
    int lane = t & 63;
    int l = lane & 31;          // quad index within row
    int eh = lane >> 5;         // edge slot 0/1

    uint2 qq = Qr[(size_t)node * 32 + l];
    int2 be = offs[node];
    int beg = be.x, cnt = be.y - be.x;

    float4 accV = make_float4(0.f, 0.f, 0.f, 0.f);
    float accZ = 0.f;

    int chunkbase = 0;
    int myidx = (beg + lane < be.y) ? csr[beg + lane] : 0;

    uint4 kvA = make_uint4(0, 0, 0, 0), kvB = make_uint4(0, 0, 0, 0);
    if (cnt > 0) kvA = KV[(size_t)__shfl(myidx, eh, 64) * 32 + l];
    if (cnt > 2) kvB = KV[(size_t)__shfl(myidx, 2 + eh, 64) * 32 + l];

    for (int e = 0; e < cnt; e += 2) {
        uint4 nkv;
        bool more = (e + 4 < cnt);
        if (more) {
            int off = e + 4 - chunkbase;         // even, <=64
            if (off == 64) {
                chunkbase += 64;
                myidx = (beg + chunkbase + lane < be.y) ? csr[beg + chunkbase + lane] : 0;
                off = 0;
            }
            nkv = KV[(size_t)__shfl(myidx, off + eh, 64) * 32 + l];
        }
        float p = fdot2(kvA.x, qq.x, fdot2(kvA.y, qq.y, 0.f));
        p += __shfl_xor(p, 1);
        p += __shfl_xor(p, 2);
        float x = fminf(fmaxf(p * 0.25f, -5.f), 5.f);
        float sc = (e + eh < cnt) ? __expf(x) : 0.f;
        accZ += sc;
        float2 va = h2f(kvA.z), vb = h2f(kvA.w);
        accV.x += sc * va.x; accV.y += sc * va.y;
        accV.z += sc * vb.x; accV.w += sc * vb.y;
        kvA = kvB;
        if (more) kvB = nkv;
    }

    // merge the two edge slots
    accZ   += __shfl_xor(accZ, 32);
    accV.x += __shfl_xor(accV.x, 32);
    accV.y += __shfl_xor(accV.y, 32);
    accV.z += __shfl_xor(accV.z, 32);
    accV.w += __shfl_xor(accV.w, 32);

    if (lane < 32) {
        if (accZ == 0.f) accZ = 0.001f;
        float inv = 1.0f / accZ;
        out[(size_t)node * 32 + l] =
            make_float4(accV.x * inv, accV.y * inv, accV.z * inv, accV.w * inv);
    }
}

// ---------------------------------------------------------------------------

extern "C" void kernel_launch(void* const* d_in, const int* in_sizes, int n_in,
                              void* d_out, int out_size, void* d_ws, size_t ws_size,
                              hipStream_t stream)
{
    const float* h   = (const float*)d_in[0];
    const int*   src = (const int*)d_in[1];
    const int*   dst = (const int*)d_in[2];
    const float* p   = (const float*)d_in[3];
    const float* q   = (const float*)d_in[4];
    const float* wv  = (const float*)d_in[5];
    float* out = (float*)d_out;

    const int N = in_sizes[0] / 128;
    const int E = in_sizes[1];
    const int nbkt = (N + 127) >> BKT_SHIFT;   // 391 for N=50000 (<=512 assumed)

    unsigned* KV = (unsigned*)d_ws;                        // N*128 uints (25.6MB)
    __half* Qh   = (__half*)(KV + (size_t)N * 128);        // N*128 halves (12.8MB)
    unsigned* ebuf = (unsigned*)(Qh + (size_t)N * 128);    // nbkt*BKT_CAP packed (8MB)
    int* csr     = (int*)(ebuf + (size_t)nbkt * BKT_CAP);  // nbkt*BKT_CAP (8MB)
    int2* offs   = (int2*)(csr + (size_t)nbkt * BKT_CAP);  // N
    int* bucket_cursor = (int*)(offs + N);                 // nbkt (<=512)
    __half* Wt   = (__half*)(bucket_cursor + 512);         // 3*128*128 halves (98KB)

    (void)hipMemsetAsync(bucket_cursor, 0, 512 * sizeof(int), stream);

    wt_convert_kernel<<<192, 256, 0, stream>>>(q, p, wv, Wt);

    int nblk_e = (E + EPB - 1) / EPB;
    bucket_scatter_kernel<<<nblk_e, 256, 0, stream>>>(src, dst, bucket_cursor, ebuf, E, nbkt);

    gemm_kqv_kernel<<<(N + HNODE - 1) / HNODE, 256, 0, stream>>>(h, Wt, KV, Qh, N);

    fine_scatter_kernel<<<nbkt, 256, 0, stream>>>(ebuf, bucket_cursor, offs, csr, N, nbkt);

    aggregate_kernel<<<(N + 3) / 4, 256, 0, stream>>>(
        (const uint4*)KV, (const uint2*)Qh, offs, csr, (float4*)out, N);
}

// Round 11
// 246.405 us; speedup vs baseline: 1.0267x; 1.0267x over previous
//
#include <hip/hip_runtime.h>
#include <hip/hip_fp16.h>

// ---------------------------------------------------------------------------
// IN=128, H=8, R=16, D=16 -> H*R = H*D = 128
// K = h @ q, Q = h @ p, V = h @ Wv   (K uses weight "q", Q uses weight "p")
// score = exp(clip((K[src]*Q[dst]).sum(r)/4, -5, 5))
// out = seg_sum(score*V[src], dst) / max(seg_sum(score,dst), eps-fixup)
//
// GEMM: mfma_f32_16x16x32_f16, A=W / B=h: lane's C frag = 4 consecutive output
// cols of one node -> in-register fp16 pack, direct stores. KV interleaved
// fp16 (512B/row). Aggregate: wave/node, 2 edge slots, double-buffered.
// CSR: bucket scatter + fine sort, both with LDS-staged COALESCED writes
// (R10 lesson: per-lane scattered 4B global stores = 64 partial lines/inst
// was the hidden ~90us in the CSR chain).
// ---------------------------------------------------------------------------

#define HNODE 64        // nodes per GEMM block
#define EPB   8192      // edges per block in bucket scatter
#define BKT_SHIFT 7     // 128 nodes per bucket
#define BKT_CAP 5120    // >= bucket mean 4092 + 16 sigma; 5120/256 = 20 slots

typedef _Float16 f16x8 __attribute__((ext_vector_type(8)));
typedef float    f32x4 __attribute__((ext_vector_type(4)));
typedef _Float16 hv2   __attribute__((ext_vector_type(2)));

__device__ __forceinline__ float fdot2(unsigned a, unsigned b, float c) {
#if __has_builtin(__builtin_amdgcn_fdot2)
    return __builtin_amdgcn_fdot2(__builtin_bit_cast(hv2, a),
                                  __builtin_bit_cast(hv2, b), c, false);
#else
    __half2 ah = *(__half2*)&a, bh = *(__half2*)&b;
    float2 af = __half22float2(ah), bf = __half22float2(bh);
    return c + af.x * bf.x + af.y * bf.y;
#endif
}

__device__ __forceinline__ float2 h2f(unsigned u) {
    __half2 hh = *(__half2*)&u;
    return __half22float2(hh);
}

__device__ __forceinline__ unsigned pack2(float a, float b) {
    __half2 hh = __floats2half2_rn(a, b);
    return *(unsigned*)&hh;
}

// ---------------- Weight transpose+convert: W[k][n] fp32 -> Wt[m][n][k] fp16
__global__ __launch_bounds__(256) void wt_convert_kernel(
    const float* __restrict__ Wq, const float* __restrict__ Wp,
    const float* __restrict__ Wv, __half* __restrict__ Wt)
{
    int o = blockIdx.x * 256 + threadIdx.x;      // 3*128*128 total
    int m = o >> 14, rem = o & 16383;
    int nn = rem >> 7, kk = rem & 127;
    const float* W = (m == 0) ? Wq : (m == 1) ? Wp : Wv;
    Wt[o] = __float2half(W[kk * 128 + nn]);
}

// ---------------- MFMA GEMM: h @ {q,p,Wv} -> KV interleaved + Q -------------
__global__ __launch_bounds__(256) void gemm_kqv_kernel(
    const float* __restrict__ h, const __half* __restrict__ Wt,
    unsigned* __restrict__ KV, __half* __restrict__ Q, int n)
{
    __shared__ __align__(16) _Float16 ws[128 * 136];   // one weight matrix

    const int t = threadIdx.x;
    const int wid = t >> 6, lane = t & 63;
    const int node0 = blockIdx.x * HNODE;
    const int mrow = lane & 15, quad = lane >> 4;

    const int row = node0 + wid * 16 + mrow;
    const bool rowvalid = (row < n);
    const int rowc = rowvalid ? row : (n - 1);

    f16x8 hfr[4];
    #pragma unroll
    for (int s = 0; s < 4; s++) {
        const float4* hp = (const float4*)(h + (size_t)rowc * 128 + quad * 8 + 32 * s);
        float4 f0 = hp[0], f1 = hp[1];
        f16x8 a;
        a[0] = (_Float16)f0.x; a[1] = (_Float16)f0.y;
        a[2] = (_Float16)f0.z; a[3] = (_Float16)f0.w;
        a[4] = (_Float16)f1.x; a[5] = (_Float16)f1.y;
        a[6] = (_Float16)f1.z; a[7] = (_Float16)f1.w;
        hfr[s] = a;
    }

    f32x4 acc[3][8];
    #pragma unroll
    for (int m = 0; m < 3; m++)
        #pragma unroll
        for (int ct = 0; ct < 8; ct++) acc[m][ct] = (f32x4){0.f, 0.f, 0.f, 0.f};

    #pragma unroll
    for (int m = 0; m < 3; m++) {
        __syncthreads();
        {
            const uint4* wg = (const uint4*)(Wt + (size_t)m * 16384);
            #pragma unroll
            for (int i = 0; i < 8; i++) {
                int idx = t * 8 + i;            // 0..2047
                int r = idx >> 4, seg = idx & 15;
                *(uint4*)(ws + r * 136 + seg * 8) = wg[idx];
            }
        }
        __syncthreads();
        #pragma unroll
        for (int s = 0; s < 4; s++) {
            #pragma unroll
            for (int ct = 0; ct < 8; ct++) {
                f16x8 a = *(const f16x8*)(ws + (ct * 16 + mrow) * 136 + quad * 8 + 32 * s);
                acc[m][ct] = __builtin_amdgcn_mfma_f32_16x16x32_f16(a, hfr[s], acc[m][ct], 0, 0, 0);
            }
        }
    }

    if (rowvalid) {
        unsigned* kvrow = KV + (size_t)row * 128;
        __half*   qrow  = Q  + (size_t)row * 128;
        #pragma unroll
        for (int ct = 0; ct < 8; ct++) {
            int qd = ct * 4 + quad;            // quad index 0..31
            uint4 ov;
            ov.x = pack2(acc[0][ct][0], acc[0][ct][1]);   // K pair
            ov.y = pack2(acc[0][ct][2], acc[0][ct][3]);
            ov.z = pack2(acc[2][ct][0], acc[2][ct][1]);   // V pair
            ov.w = pack2(acc[2][ct][2], acc[2][ct][3]);
            *(uint4*)(kvrow + 4 * qd) = ov;
            uint2 qv;
            qv.x = pack2(acc[1][ct][0], acc[1][ct][1]);
            qv.y = pack2(acc[1][ct][2], acc[1][ct][3]);
            *(uint2*)(qrow + 4 * qd) = qv;
        }
    }
}

// ---------------- CSR stage 1: bucket scatter, LDS-sorted coalesced writes --
// pass1: rank via LDS histogram atomic (regs). pass2: block-local bucket sort
// into 64KB LDS (packed (dst<<18)|src, 34 bits). pass3: lane-consecutive
// emission -> full-line global stores into per-bucket reserved chunks.
__global__ __launch_bounds__(256) void bucket_scatter_kernel(
    const int* __restrict__ src, const int* __restrict__ dst,
    int* __restrict__ bucket_cursor, unsigned* __restrict__ ebuf, int E, int nbkt)
{
    __shared__ int cnt[512];
    __shared__ int lofs[512];
    __shared__ int gstart[512];
    __shared__ int ts[256];
    __shared__ int tot_sh;
    __shared__ unsigned long long sorted[EPB];   // 64 KB

    int t = threadIdx.x;
    for (int i = t; i < 512; i += 256) cnt[i] = 0;
    __syncthreads();

    int4 sv[8], dv[8], rk[8];
    int base = blockIdx.x * EPB + t * 4;
    #pragma unroll
    for (int r = 0; r < 8; r++) {
        int i = base + r * 1024;
        if (i + 3 < E) {
            sv[r] = *(const int4*)(src + i);
            dv[r] = *(const int4*)(dst + i);
        } else {
            int tsrc[4], tdst[4];
            for (int k = 0; k < 4; k++) {
                int j = i + k;
                tsrc[k] = (j < E) ? src[j] : 0;
                tdst[k] = (j < E) ? dst[j] : -1;
            }
            sv[r] = make_int4(tsrc[0], tsrc[1], tsrc[2], tsrc[3]);
            dv[r] = make_int4(tdst[0], tdst[1], tdst[2], tdst[3]);
        }
        rk[r].x = (dv[r].x >= 0) ? atomicAdd(&cnt[dv[r].x >> BKT_SHIFT], 1) : 0;
        rk[r].y = (dv[r].y >= 0) ? atomicAdd(&cnt[dv[r].y >> BKT_SHIFT], 1) : 0;
        rk[r].z = (dv[r].z >= 0) ? atomicAdd(&cnt[dv[r].z >> BKT_SHIFT], 1) : 0;
        rk[r].w = (dv[r].w >= 0) ? atomicAdd(&cnt[dv[r].w >> BKT_SHIFT], 1) : 0;
    }
    __syncthreads();

    // exclusive scan over 512 bucket counts: thread t owns elements 2t, 2t+1
    int c0 = cnt[2 * t], c1 = cnt[2 * t + 1];
    int ps = c0 + c1;
    ts[t] = ps; __syncthreads();
    for (int off = 1; off < 256; off <<= 1) {
        int x = ts[t];
        int y = (t >= off) ? ts[t - off] : 0;
        __syncthreads();
        ts[t] = x + y;
        __syncthreads();
    }
    int pbase = ts[t] - ps;          // exclusive prefix of pair
    lofs[2 * t] = pbase;
    lofs[2 * t + 1] = pbase + c0;
    if (t == 255) tot_sh = ts[255];
    // reserve global chunks (one returning atomic per non-empty bucket)
    for (int i = t; i < nbkt; i += 256)
        gstart[i] = cnt[i] ? atomicAdd(&bucket_cursor[i], cnt[i]) : 0;
    __syncthreads();

    // pass2: place edges into block-local sorted LDS
    #pragma unroll
    for (int r = 0; r < 8; r++) {
        int s, d;
        d = dv[r].x; if (d >= 0) { s = sv[r].x; sorted[lofs[d >> BKT_SHIFT] + rk[r].x] = ((unsigned long long)d << 18) | (unsigned)s; }
        d = dv[r].y; if (d >= 0) { s = sv[r].y; sorted[lofs[d >> BKT_SHIFT] + rk[r].y] = ((unsigned long long)d << 18) | (unsigned)s; }
        d = dv[r].z; if (d >= 0) { s = sv[r].z; sorted[lofs[d >> BKT_SHIFT] + rk[r].z] = ((unsigned long long)d << 18) | (unsigned)s; }
        d = dv[r].w; if (d >= 0) { s = sv[r].w; sorted[lofs[d >> BKT_SHIFT] + rk[r].w] = ((unsigned long long)d << 18) | (unsigned)s; }
    }
    __syncthreads();

    // pass3: lane-consecutive emission -> coalesced stores
    int tot = tot_sh;
    #pragma unroll
    for (int j = 0; j < 32; j++) {
        int i = j * 256 + t;
        if (i < tot) {
            unsigned long long e = sorted[i];
            int d = (int)(e >> 18);
            int b = d >> BKT_SHIFT;
            int pos = gstart[b] + (i - lofs[b]);
            if (pos < BKT_CAP)
                ebuf[(size_t)b * BKT_CAP + pos] =
                    ((unsigned)(d & 127) << 18) | (unsigned)(e & 0x3FFFFu);
        }
    }
}

// ---------------- CSR stage 2: fine sort, LDS-staged coalesced csr writes ---
__global__ __launch_bounds__(256) void fine_scatter_kernel(
    const unsigned* __restrict__ ebuf, const int* __restrict__ bucket_cursor,
    int2* __restrict__ offs, int* __restrict__ csr, int N, int nbkt)
{
    __shared__ int ldeg[128];
    __shared__ int lstart[128];          // block-local (0-based) node starts
    __shared__ int lcsr[BKT_CAP];        // 20 KB staging
    int b = blockIdx.x, t = threadIdx.x;
    int node_base = b << BKT_SHIFT;
    int seg0 = b * BKT_CAP;
    int cnt = bucket_cursor[b];
    if (cnt > BKT_CAP) cnt = BKT_CAP;

    if (t < 128) ldeg[t] = 0;
    __syncthreads();

    unsigned pv[20];
    int rk[20];
    #pragma unroll
    for (int j = 0; j < 20; j++) {
        int i = t + j * 256;
        bool ok = (i < cnt);
        unsigned v = ok ? ebuf[seg0 + i] : 0u;
        pv[j] = v;
        rk[j] = ok ? atomicAdd(&ldeg[v >> 18], 1) : 0;
    }
    __syncthreads();

    int mydeg = (t < 128) ? ldeg[t] : 0;
    for (int off = 1; off < 128; off <<= 1) {
        int y = (t >= off && t < 128) ? ldeg[t - off] : 0;
        __syncthreads();
        if (t < 128) ldeg[t] += y;
        __syncthreads();
    }
    if (t < 128) {
        int lbeg = ldeg[t] - mydeg;      // block-local exclusive
        lstart[t] = lbeg;
        int node = node_base + t;
        if (node < N) offs[node] = make_int2(seg0 + lbeg, seg0 + lbeg + mydeg);
    }
    __syncthreads();

    // scatter into LDS (random, cheap), ...
    #pragma unroll
    for (int j = 0; j < 20; j++) {
        int i = t + j * 256;
        if (i < cnt)
            lcsr[lstart[pv[j] >> 18] + rk[j]] = (int)(pv[j] & 0x3FFFFu);
    }
    __syncthreads();

    // ... then copy out coalesced
    for (int i = t; i < cnt; i += 256)
        csr[seg0 + i] = lcsr[i];
}

// ---------------- Aggregation: wave/node, 2 slots, double-buffered prefetch -
__global__ __launch_bounds__(256) void aggregate_kernel(
    const uint4* __restrict__ KV, const uint2* __restrict__ Qr,
    const int2* __restrict__ offs, const int* __restrict__ csr,
    float4* __restrict__ out, int n)
{
    int t = threadIdx.x;
    int node = blockIdx.x * 4 + (t >> 6);
    if (node >= n) return;
    int lane = t & 63;
    int l = lane & 31;          // quad index within row
    int eh = lane >> 5;         // edge slot 0/1

    uint2 qq = Qr[(size_t)node * 32 + l];
    int2 be = offs[node];
    int beg = be.x, cnt = be.y - be.x;

    float4 accV = make_float4(0.f, 0.f, 0.f, 0.f);
    float accZ = 0.f;

    int chunkbase = 0;
    int myidx = (beg + lane < be.y) ? csr[beg + lane] : 0;

    uint4 kvA = make_uint4(0, 0, 0, 0), kvB = make_uint4(0, 0, 0, 0);
    if (cnt > 0) kvA = KV[(size_t)__shfl(myidx, eh, 64) * 32 + l];
    if (cnt > 2) kvB = KV[(size_t)__shfl(myidx, 2 + eh, 64) * 32 + l];

    for (int e = 0; e < cnt; e += 2) {
        uint4 nkv;
        bool more = (e + 4 < cnt);
        if (more) {
            int off = e + 4 - chunkbase;         // even, <=64
            if (off == 64) {
                chunkbase += 64;
                myidx = (beg + chunkbase + lane < be.y) ? csr[beg + chunkbase + lane] : 0;
                off = 0;
            }
            nkv = KV[(size_t)__shfl(myidx, off + eh, 64) * 32 + l];
        }
        float p = fdot2(kvA.x, qq.x, fdot2(kvA.y, qq.y, 0.f));
        p += __shfl_xor(p, 1);
        p += __shfl_xor(p, 2);
        float x = fminf(fmaxf(p * 0.25f, -5.f), 5.f);
        float sc = (e + eh < cnt) ? __expf(x) : 0.f;
        accZ += sc;
        float2 va = h2f(kvA.z), vb = h2f(kvA.w);
        accV.x += sc * va.x; accV.y += sc * va.y;
        accV.z += sc * vb.x; accV.w += sc * vb.y;
        kvA = kvB;
        if (more) kvB = nkv;
    }

    accZ   += __shfl_xor(accZ, 32);
    accV.x += __shfl_xor(accV.x, 32);
    accV.y += __shfl_xor(accV.y, 32);
    accV.z += __shfl_xor(accV.z, 32);
    accV.w += __shfl_xor(accV.w, 32);

    if (lane < 32) {
        if (accZ == 0.f) accZ = 0.001f;
        float inv = 1.0f / accZ;
        out[(size_t)node * 32 + l] =
            make_float4(accV.x * inv, accV.y * inv, accV.z * inv, accV.w * inv);
    }
}

// ---------------------------------------------------------------------------

extern "C" void kernel_launch(void* const* d_in, const int* in_sizes, int n_in,
                              void* d_out, int out_size, void* d_ws, size_t ws_size,
                              hipStream_t stream)
{
    const float* h   = (const float*)d_in[0];
    const int*   src = (const int*)d_in[1];
    const int*   dst = (const int*)d_in[2];
    const float* p   = (const float*)d_in[3];
    const float* q   = (const float*)d_in[4];
    const float* wv  = (const float*)d_in[5];
    float* out = (float*)d_out;

    const int N = in_sizes[0] / 128;
    const int E = in_sizes[1];
    const int nbkt = (N + 127) >> BKT_SHIFT;   // 391 for N=50000 (<=512 assumed)

    unsigned* KV = (unsigned*)d_ws;                        // N*128 uints (25.6MB)
    __half* Qh   = (__half*)(KV + (size_t)N * 128);        // N*128 halves (12.8MB)
    unsigned* ebuf = (unsigned*)(Qh + (size_t)N * 128);    // nbkt*BKT_CAP packed (8MB)
    int* csr     = (int*)(ebuf + (size_t)nbkt * BKT_CAP);  // nbkt*BKT_CAP (8MB)
    int2* offs   = (int2*)(csr + (size_t)nbkt * BKT_CAP);  // N
    int* bucket_cursor = (int*)(offs + N);                 // nbkt (<=512)
    __half* Wt   = (__half*)(bucket_cursor + 512);         // 3*128*128 halves (98KB)

    (void)hipMemsetAsync(bucket_cursor, 0, 512 * sizeof(int), stream);

    wt_convert_kernel<<<192, 256, 0, stream>>>(q, p, wv, Wt);

    int nblk_e = (E + EPB - 1) / EPB;
    bucket_scatter_kernel<<<nblk_e, 256, 0, stream>>>(src, dst, bucket_cursor, ebuf, E, nbkt);

    gemm_kqv_kernel<<<(N + HNODE - 1) / HNODE, 256, 0, stream>>>(h, Wt, KV, Qh, N);

    fine_scatter_kernel<<<nbkt, 256, 0, stream>>>(ebuf, bucket_cursor, offs, csr, N, nbkt);

    aggregate_kernel<<<(N + 3) / 4, 256, 0, stream>>>(
        (const uint4*)KV, (const uint2*)Qh, offs, csr, (float4*)out, N);
}